// Round 4
// baseline (437.368 us; speedup 1.0000x reference)
//
#include <hip/hip_runtime.h>
#include <stdint.h>

typedef unsigned short u16;
typedef __attribute__((ext_vector_type(8))) short short8;  // 8 bf16 (4 VGPRs)
typedef __attribute__((ext_vector_type(4))) float f32x4;   // MFMA C/D

#define B_ 8
#define T_ 4096
#define C_ 1024
#define H_ 128

#if __has_builtin(__builtin_amdgcn_exp2f)
#define EXP2(x) __builtin_amdgcn_exp2f(x)
#else
#define EXP2(x) exp2f(x)
#endif

__device__ __forceinline__ u16 f2bf(float f) {
  union { float f; uint32_t u; } v; v.f = f;
  uint32_t r = v.u + 0x7fffu + ((v.u >> 16) & 1u);  // RNE
  return (u16)(r >> 16);
}

// async global->LDS, 16B per lane; LDS dest = uniform base + lane*16
#define GLOAD_LDS16(gptr, lptr)                                               \
  __builtin_amdgcn_global_load_lds(                                           \
      (const __attribute__((address_space(1))) uint32_t*)(gptr),              \
      (__attribute__((address_space(3))) uint32_t*)(lptr), 16, 0, 0)

// ---------------------------------------------------------------------------
// x fp32 -> bf16 (memory-bound, read 134 MB write 67 MB)
// ---------------------------------------------------------------------------
__global__ __launch_bounds__(256) void xconv_kernel(
    const float* __restrict__ x, u16* __restrict__ xb) {
  size_t g = ((size_t)blockIdx.x * 256 + threadIdx.x) * 8;
  float4 a = *(const float4*)(x + g);
  float4 b = *(const float4*)(x + g + 4);
  u16 o[8] = {f2bf(a.x), f2bf(a.y), f2bf(a.z), f2bf(a.w),
              f2bf(b.x), f2bf(b.y), f2bf(b.z), f2bf(b.w)};
  *(uint4*)(xb + g) = *(const uint4*)o;
}

// ---------------------------------------------------------------------------
// W conversion: Wq|Wk|Wv fp32 -> Wb bf16 [384][1024], Wq pre-scaled 1/sqrt(128)
// ---------------------------------------------------------------------------
__global__ __launch_bounds__(256) void wconv_kernel(
    const float* __restrict__ Wq, const float* __restrict__ Wk,
    const float* __restrict__ Wv, u16* __restrict__ Wb) {
  int g = (blockIdx.x * 256 + threadIdx.x) * 8;
  int head = g >> 17;
  int off  = g & 131071;
  const float* W = (head == 0) ? Wq : (head == 1) ? Wk : Wv;
  float s = (head == 0) ? 0.08838834764831845f : 1.0f;
  float4 a = *(const float4*)(W + off);
  float4 b = *(const float4*)(W + off + 4);
  u16 o[8] = {f2bf(a.x * s), f2bf(a.y * s), f2bf(a.z * s), f2bf(a.w * s),
              f2bf(b.x * s), f2bf(b.y * s), f2bf(b.z * s), f2bf(b.w * s)};
  *(uint4*)(Wb + g) = *(const uint4*)o;
}

// ---------------------------------------------------------------------------
// QKV projection: y = xb @ Wb^T. M=64/block (512 blocks x 512 thr), N=384,
// K=1024 in BK=64 steps. ALL staging via global_load_lds in FRAGMENT ORDER:
// segment = 64 lanes x 16B, lane i holds A/B[idx=i&15][k=(i>>4)*8..+8].
// Frag loads are ds_read_b128 at base+lane*16 (conflict-free).
// ---------------------------------------------------------------------------
__global__ __launch_bounds__(512, 4) void proj_kernel(
    const u16* __restrict__ xb, const u16* __restrict__ Wb,
    u16* __restrict__ qo, u16* __restrict__ ko, u16* __restrict__ vto) {
  __shared__ u16 Xf[8 * 512];    // 8 segs  (4 m-tiles x 2 kb)   8 KB
  __shared__ u16 Wf[48 * 512];   // 48 segs (24 n-tiles x 2 kb) 48 KB

  const int bm   = blockIdx.x;
  const int tid  = threadIdx.x;
  const int wave = tid >> 6;
  const int lane = tid & 63;
  const int m    = lane & 15;
  const int q4   = lane >> 4;
  const int rowg = wave & 1;     // 2 row-groups x 32 rows
  const int colg = wave >> 1;    // 4 col-groups x 96 cols

  const int fr = lane & 15;      // fragment row within tile
  const int fk = (lane >> 4) * 8;

  f32x4 acc[12] = {};            // [half(2)][nb(6)]

  for (int kc = 0; kc < C_; kc += 64) {
    // stage 56 segments, 7 per wave
    #pragma unroll
    for (int i = 0; i < 7; ++i) {
      int seg = wave * 7 + i;
      if (seg < 8) {
        int tm = seg >> 1, kb = seg & 1;
        GLOAD_LDS16(xb + (size_t)(bm * 64 + tm * 16 + fr) * C_ + kc + kb * 32 + fk,
                    &Xf[seg * 512]);
      } else {
        int w = seg - 8;
        int nt = w >> 1, kb = w & 1;
        GLOAD_LDS16(Wb + (size_t)(nt * 16 + fr) * C_ + kc + kb * 32 + fk,
                    &Wf[w * 512]);
      }
    }
    __syncthreads();

    #pragma unroll
    for (int kb = 0; kb < 2; ++kb) {
      short8 af0 = *(const short8*)&Xf[((rowg * 2 + 0) * 2 + kb) * 512 + lane * 8];
      short8 af1 = *(const short8*)&Xf[((rowg * 2 + 1) * 2 + kb) * 512 + lane * 8];
      #pragma unroll
      for (int nb = 0; nb < 6; ++nb) {
        short8 bf = *(const short8*)&Wf[((colg * 6 + nb) * 2 + kb) * 512 + lane * 8];
        acc[nb]     = __builtin_amdgcn_mfma_f32_16x16x32_bf16(af0, bf, acc[nb], 0, 0, 0);
        acc[6 + nb] = __builtin_amdgcn_mfma_f32_16x16x32_bf16(af1, bf, acc[6 + nb], 0, 0, 0);
      }
    }
    __syncthreads();   // all frag reads done before next staging overwrites
  }

  // epilogue: C/D row = q4*4+r, col = m. cols 0-127: q, 128-255: k, 256+: v->vT
  #pragma unroll
  for (int half = 0; half < 2; ++half) {
    const int rowoff = rowg * 32 + half * 16 + q4 * 4;
    #pragma unroll
    for (int nb = 0; nb < 6; ++nb) {
      int col = colg * 96 + nb * 16 + m;
      f32x4 a = acc[half * 6 + nb];
      if (col < 128) {
        #pragma unroll
        for (int r = 0; r < 4; ++r)
          qo[(size_t)(bm * 64 + rowoff + r) * H_ + col] = f2bf(a[r]);
      } else if (col < 256) {
        #pragma unroll
        for (int r = 0; r < 4; ++r)
          ko[(size_t)(bm * 64 + rowoff + r) * H_ + (col - 128)] = f2bf(a[r]);
      } else {
        int b = bm >> 6;
        int t = (bm & 63) * 64 + rowoff;
        u16* vp = vto + (size_t)b * H_ * T_ + (size_t)(col - 256) * T_ + t;
        #pragma unroll
        for (int r = 0; r < 4; ++r) vp[r] = f2bf(a[r]);
      }
    }
  }
}

// ---------------------------------------------------------------------------
// Flash attention, causal, no-max softmax. Br=128 (8 waves x 16 q-rows, 512
// thr). Task = (batch, j=qtile128, ck): keys [ck*16, min(ck*16+16, 2j+2)) of
// 64-wide kt tiles. grid=1024, heavy-first (ck fastest within j desc), empty
// tasks exit. j<8: single chunk -> direct out; else partials po/pl.
// ---------------------------------------------------------------------------
__global__ __launch_bounds__(512, 4) void attn_kernel(
    const u16* __restrict__ q, const u16* __restrict__ k,
    const u16* __restrict__ vt, float* __restrict__ out,
    float* __restrict__ po, float* __restrict__ pl) {
  __shared__ u16 Kl[64 * 136];   // [s][h] pad 136           17.4 KB
  __shared__ u16 Vl[128 * 72];   // [h][s] pad 72             18.4 KB
  __shared__ u16 Pl[8][16 * 72]; // per-wave P strip pad 72   18.4 KB

  const int bid   = blockIdx.x;
  const int batch = bid & 7;       // == XCD alias: K/V pinned per-XCD L2
  const int c     = bid >> 3;      // 0..127
  const int ck    = c & 3;
  const int j     = 31 - (c >> 2); // heavy q-tiles first
  const int k0    = ck * 16;
  const int kend  = min(k0 + 16, 2 * j + 2);
  if (k0 >= kend) return;          // empty task
  const bool single = (j < 8);

  const int tid  = threadIdx.x;
  const int wave = tid >> 6;
  const int lane = tid & 63;
  const int m    = lane & 15;
  const int q4   = lane >> 4;

  const size_t bbase = (size_t)batch * T_ * H_;
  const u16* vbase   = vt + (size_t)batch * H_ * T_;

  // Q fragments (A layout); q pre-scaled by 1/sqrt(128)
  short8 qf[4];
  {
    const u16* qp = q + bbase + (size_t)(j * 128 + wave * 16 + m) * H_;
    #pragma unroll
    for (int kb = 0; kb < 4; ++kb)
      qf[kb] = *(const short8*)(qp + kb * 32 + q4 * 8);
  }

  // staging (512 threads: 2 x uint4 each per tile)
  uint4 kr[2], vr[2];
  const int krow = tid >> 3, kcol = (tid & 7) * 16;   // K: 64 x 128
  const int vrow = tid >> 2, vcol = (tid & 3) * 16;   // V: 128 x 64

#define LOAD_TILES(KT)                                                        \
  {                                                                           \
    const u16* kp = k + bbase + (size_t)((KT) * 64 + krow) * H_ + kcol;       \
    kr[0] = *(const uint4*)kp;                                                \
    kr[1] = *(const uint4*)(kp + 8);                                          \
    const u16* vp = vbase + (size_t)vrow * T_ + (KT) * 64 + vcol;             \
    vr[0] = *(const uint4*)vp;                                                \
    vr[1] = *(const uint4*)(vp + 8);                                          \
  }
#define STORE_TILES()                                                         \
  {                                                                           \
    *(uint4*)&Kl[krow * 136 + kcol]     = kr[0];                              \
    *(uint4*)&Kl[krow * 136 + kcol + 8] = kr[1];                              \
    *(uint4*)&Vl[vrow * 72 + vcol]      = vr[0];                              \
    *(uint4*)&Vl[vrow * 72 + vcol + 8]  = vr[1];                              \
  }

  float li[4] = {0.f, 0.f, 0.f, 0.f};
  f32x4 o[8] = {};
  const float L2E = 1.4426950408889634f;
  const float NEGINF = -__builtin_inff();

  LOAD_TILES(k0);
  STORE_TILES();
  __syncthreads();

  for (int kt = k0; kt < kend; ++kt) {
    if (kt + 1 < kend) LOAD_TILES(kt + 1);

    // S strip (16x64) = Q K^T
    f32x4 s[4];
    #pragma unroll
    for (int nb = 0; nb < 4; ++nb) {
      f32x4 a = {};
      #pragma unroll
      for (int kb = 0; kb < 4; ++kb) {
        short8 kf = *(const short8*)&Kl[(nb * 16 + m) * 136 + kb * 32 + q4 * 8];
        a = __builtin_amdgcn_mfma_f32_16x16x32_bf16(qf[kb], kf, a, 0, 0, 0);
      }
      s[nb] = a;
    }

    if (kt >= 2 * j) {  // diagonal tiles: mask col > row (block-relative)
      #pragma unroll
      for (int nb = 0; nb < 4; ++nb)
        #pragma unroll
        for (int r = 0; r < 4; ++r) {
          int colr = (kt - 2 * j) * 64 + nb * 16 + m;
          int rowb = wave * 16 + q4 * 4 + r;
          if (colr > rowb) s[nb][r] = NEGINF;
        }
    }

    // p = exp2(s*log2e) -- no max subtraction, no cross-lane ops in loop
    #pragma unroll
    for (int nb = 0; nb < 4; ++nb)
      #pragma unroll
      for (int r = 0; r < 4; ++r) {
        float p = EXP2(s[nb][r] * L2E);
        li[r] += p;
        Pl[wave][(q4 * 4 + r) * 72 + nb * 16 + m] = f2bf(p);
      }

    __asm__ __volatile__("s_waitcnt lgkmcnt(0)" ::: "memory");

    // O += P V
    #pragma unroll
    for (int kb2 = 0; kb2 < 2; ++kb2) {
      short8 pf = *(const short8*)&Pl[wave][m * 72 + kb2 * 32 + q4 * 8];
      #pragma unroll
      for (int nb = 0; nb < 8; ++nb) {
        short8 vf = *(const short8*)&Vl[(nb * 16 + m) * 72 + kb2 * 32 + q4 * 8];
        o[nb] = __builtin_amdgcn_mfma_f32_16x16x32_bf16(pf, vf, o[nb], 0, 0, 0);
      }
    }

    __syncthreads();
    if (kt + 1 < kend) STORE_TILES();
    __syncthreads();
  }

  // reduce li across the 16 lanes sharing q4
  #pragma unroll
  for (int r = 0; r < 4; ++r) {
    float t0 = li[r];
    t0 += __shfl_xor(t0, 1, 64);
    t0 += __shfl_xor(t0, 2, 64);
    t0 += __shfl_xor(t0, 4, 64);
    t0 += __shfl_xor(t0, 8, 64);
    li[r] = t0;
  }

  if (single) {
    float* op = out + bbase + (size_t)(j * 128 + wave * 16) * H_;
    #pragma unroll
    for (int nb = 0; nb < 8; ++nb)
      #pragma unroll
      for (int r = 0; r < 4; ++r)
        op[(q4 * 4 + r) * H_ + nb * 16 + m] = o[nb][r] / li[r];
  } else {
    const size_t slot = (size_t)(batch * 24 + (j - 8)) * 4 + ck;
    float* pp = po + slot * 16384 + (size_t)(wave * 16) * 128;
    #pragma unroll
    for (int nb = 0; nb < 8; ++nb)
      #pragma unroll
      for (int r = 0; r < 4; ++r)
        pp[(q4 * 4 + r) * 128 + nb * 16 + m] = o[nb][r];
    if (m == 0) {
      #pragma unroll
      for (int r = 0; r < 4; ++r)
        pl[slot * 128 + wave * 16 + q4 * 4 + r] = li[r];
    }
  }
}

// ---------------------------------------------------------------------------
// Combine: out = sum_ck o_ck / sum_ck l_ck  (additive: shared implicit max=0)
// ---------------------------------------------------------------------------
__global__ __launch_bounds__(256) void combine_kernel(
    const float* __restrict__ po, const float* __restrict__ pl,
    float* __restrict__ out) {
  int gid = blockIdx.x * 256 + threadIdx.x;   // 1,048,576 threads
  int h4  = (gid & 31) * 4;
  int t   = (gid >> 5) & 4095;
  int b   = gid >> 17;
  int j   = t >> 7;
  if (j < 8) return;                          // written directly by attn
  int row = t & 127;
  int nc  = (j >> 3) + 1;                     // 2/3/4 chunks
  float4 s = {0.f, 0.f, 0.f, 0.f};
  float l = 0.f;
  for (int ck = 0; ck < nc; ++ck) {
    size_t slot = (size_t)(b * 24 + (j - 8)) * 4 + ck;
    float4 p = *(const float4*)(po + slot * 16384 + (size_t)row * 128 + h4);
    s.x += p.x; s.y += p.y; s.z += p.z; s.w += p.w;
    l += pl[slot * 128 + row];
  }
  float inv = 1.0f / l;
  float4 r; r.x = s.x * inv; r.y = s.y * inv; r.z = s.z * inv; r.w = s.w * inv;
  *(float4*)(out + ((size_t)b * T_ + t) * H_ + h4) = r;
}

// ---------------------------------------------------------------------------
extern "C" void kernel_launch(void* const* d_in, const int* in_sizes, int n_in,
                              void* d_out, int out_size, void* d_ws,
                              size_t ws_size, hipStream_t stream) {
  const float* x  = (const float*)d_in[0];
  const float* Wq = (const float*)d_in[1];
  const float* Wk = (const float*)d_in[2];
  const float* Wv = (const float*)d_in[3];

  const size_t nx = (size_t)B_ * T_ * C_;  // 33,554,432
  const size_t n  = (size_t)B_ * T_ * H_;  //  4,194,304
  u16* xb  = (u16*)d_ws;                   // 67.1 MB (dead after proj)
  u16* qb  = xb + nx;
  u16* kb  = qb + n;
  u16* vtb = kb + n;                       // v transposed [B][H][T]
  u16* Wbb = vtb + n;                      // 384x1024 bf16
  float* pl = (float*)(Wbb + 393216);      // 768*128 fp32 = 0.4 MB
  float* po = (float*)d_ws;                // overlays dead xb: 50.3 MB

  xconv_kernel<<<dim3(16384), dim3(256), 0, stream>>>(x, xb);
  wconv_kernel<<<dim3(192), dim3(256), 0, stream>>>(Wq, Wk, Wv, Wbb);
  proj_kernel<<<dim3(512), dim3(512), 0, stream>>>(xb, Wbb, qb, kb, vtb);
  attn_kernel<<<dim3(1024), dim3(512), 0, stream>>>(qb, kb, vtb, (float*)d_out, po, pl);
  combine_kernel<<<dim3(4096), dim3(256), 0, stream>>>(po, pl, (float*)d_out);
}